// Round 4
// baseline (253.810 us; speedup 1.0000x reference)
//
#include <hip/hip_runtime.h>

// FlowNet correlation: out[b, dy*9+dx, y, x] = (1/256) sum_c x1[b,c,y,x] * x2[b,c,y+dy-4,x+dx-4]
// B=4 C=256 H=W=128, 9x9 displacements, zero padding.
//
// Round-8 = round-7 structure + LDS bank-conflict fix via LANE REMAP.
//  - Diagnosis: RSC 48->44 (needed for 3 blocks/CU) made compute ds_read_b128
//    2-way conflicted: with gy=lane>>2, a HW cycle-group of 8 lanes (2 rows x
//    4 colgroups) started at banks {0,4,8,12,12,16,20,24} -> 16.8M conflict
//    cycles (~27 us/CU serialized). 44 mod 32 = 12 breaks the 2-rows/group tiling.
//  - Fix: gy = lane&15, gx = lane>>4  -> each 8-lane group = 8 DIFFERENT rows,
//    starts (44*gy) mod 32 = {0,12,24,4,16,28,8,20}: all 32 banks exactly once.
//    Lane permutation leaves the wave's global cache-line set unchanged.
//  - Staging writes remapped too (row index fastest-varying in slot space):
//    write starts 44*rr mod 32 = same perfect spread.
//  - Everything else = round-7: 6 waves (3 dy x 2 channel halves), RSC=44,
//    50688 B LDS -> 3 blocks/CU (18 waves), __launch_bounds__(384,4) (no spill),
//    32 chunks of 8 staged channels, epilogue stride 37, XCD swizzle.

#define MD 4
constexpr int Bc = 4, Cc = 256, Hc = 128, Wc = 128;
constexpr int HW = Hc * Wc;
constexpr int TH = 16, TW = 16;
constexpr int NDY = 3;                  // dy per d-group (one per wave team)
constexpr int NH  = 2;                  // channel halves (in-block K split)
constexpr int CC  = 4;                  // channels per chunk per half
constexpr int SROWS = TH + NDY - 1;     // 18 staged rows
constexpr int SCOLS = TW + 2 * MD;      // 24 staged cols
constexpr int RSC = 44;                 // padded row stride (dw); see lane remap
constexpr int CH_STRIDE = SROWS * RSC;  // 792 dw per channel
constexpr int BUF_DW = NH * CC * CH_STRIDE;        // 6336 dw per buffer
constexpr int NF4 = NH * CC * SROWS * (SCOLS / 4); // 864 float4 staging slots
constexpr int NTHR = 384;
constexpr int NSLOT = 3;                // ceil(864/384)
constexpr int NK = Cc / (NH * CC);      // 32 chunks
constexpr int EPS = 37;                 // epilogue lane stride (dw), conflict-free

__global__ __launch_bounds__(NTHR, 4)
void corr_kernel(const float* __restrict__ x1, const float* __restrict__ x2,
                 float* __restrict__ out)
{
    __shared__ float stg[2 * BUF_DW];   // 50688 B

    const int tid  = threadIdx.x;
    const int ww   = tid >> 6;          // wave id 0..5
    const int h    = (ww >= 3) ? 1 : 0; // channel half
    const int w    = ww - 3 * h;        // local dy 0..2
    const int lane = tid & 63;
    const int gy   = lane & 15;         // 0..15 tile row   (REMAPPED: row fastest)
    const int gx   = lane >> 4;         // 0..3  col-group  (4 px each)

    // ---- XCD-aware swizzle: g-siblings (same tile) differ by +8 in bid -> same XCD ----
    const int bid  = blockIdx.x;
    const int q    = bid / 24;
    const int r    = bid - q * 24;
    const int g    = r >> 3;            // d-group 0..2
    const int t    = q * 8 + (r & 7);   // tile index 0..255
    const int tx = t & 7;
    const int ty = (t >> 3) & 7;
    const int bb = t >> 6;
    const int x0 = tx * TW, y0 = ty * TH;
    const int rowbase = y0 + 3 * g - MD;   // global y of staged row 0

    // ---- hoisted staging slot descriptors (fixed per thread across chunks) ----
    // slot space: cl8 in 0..7 (0-3 = half0 ch, 4-7 = half1 ch), per channel
    // gc-major with ROW FASTEST: slot = gc*18 + rr  -> consecutive lanes write
    // consecutive rows, bank starts 44*rr mod 32 = {0,12,24,4,16,28,8,20}.
    int  s_goff[NSLOT], s_loff[NSLOT];
    bool s_val[NSLOT], s_act[NSLOT];
    #pragma unroll
    for (int s = 0; s < NSLOT; ++s) {
        int idx = tid + s * NTHR;
        bool active = idx < NF4;
        int i2  = active ? idx : 0;
        int cl8 = i2 / (SROWS * 6);
        int rem = i2 - cl8 * (SROWS * 6);
        int gc  = rem / SROWS;
        int rr  = rem - gc * SROWS;
        int ch  = (cl8 < CC) ? cl8 : (Cc / 2 + cl8 - CC);  // base channel of this slot
        int yy  = rowbase + rr;
        int xx  = x0 - 4 + 4 * gc;          // multiple of 4: float4 all-valid or all-invalid
        s_act[s]  = active;
        s_val[s]  = active && ((unsigned)yy < (unsigned)Hc) && ((unsigned)xx < (unsigned)(Wc - 3));
        s_goff[s] = ch * HW + yy * Wc + xx;
        s_loff[s] = cl8 * CH_STRIDE + rr * RSC + 4 * gc;
    }

    const float* x2b = x2 + (size_t)bb * Cc * HW;
    const float* x1b = x1 + (((size_t)bb * Cc + h * (Cc / 2)) * Hc + (y0 + gy)) * Wc
                          + x0 + 4 * gx;

    float acc[9][4];
    #pragma unroll
    for (int dx = 0; dx < 9; ++dx)
        #pragma unroll
        for (int p = 0; p < 4; ++p) acc[dx][p] = 0.f;

    const float4 f40 = make_float4(0.f, 0.f, 0.f, 0.f);
    float4 nf[NSLOT];

    // ---- prologue: stage chunk 0 (channels {0..3} and {128..131}) into buffer 0 ----
    #pragma unroll
    for (int s = 0; s < NSLOT; ++s) {
        nf[s] = f40;
        if (s_val[s]) nf[s] = *(const float4*)(x2b + s_goff[s]);
    }
    #pragma unroll
    for (int s = 0; s < NSLOT; ++s)
        if (s_act[s]) *(float4*)(&stg[s_loff[s]]) = nf[s];

    for (int k = 0; k < NK; ++k) {
        const int pb = k & 1;
        // issue global x2 prefetch for chunk k+1 (latency overlapped with compute below)
        if (k + 1 < NK) {
            const int gof = (k + 1) * CC * HW;   // both halves advance CC channels/chunk
            #pragma unroll
            for (int s = 0; s < NSLOT; ++s) {
                nf[s] = f40;
                if (s_val[s]) nf[s] = *(const float4*)(x2b + gof + s_goff[s]);
            }
        }
        __syncthreads();   // chunk k's buffer fully written; prev buffer's readers done
        // ---- compute chunk k (x1 loaded inline: L1/L2 hits, no reg pressure) ----
        #pragma unroll
        for (int cl = 0; cl < CC; ++cl) {
            const int c = k * CC + cl;                     // within-half channel index
            const float4 a4 = *(const float4*)(x1b + c * HW);
            const float* rowp = &stg[pb * BUF_DW + (h * CC + cl) * CH_STRIDE
                                     + (gy + w) * RSC + 4 * gx];
            const float4 q0 = *(const float4*)(rowp);
            const float4 q1 = *(const float4*)(rowp + 4);
            const float4 q2 = *(const float4*)(rowp + 8);
            const float v[12] = {q0.x, q0.y, q0.z, q0.w,
                                 q1.x, q1.y, q1.z, q1.w,
                                 q2.x, q2.y, q2.z, q2.w};
            const float a[4] = {a4.x, a4.y, a4.z, a4.w};
            #pragma unroll
            for (int dx = 0; dx < 9; ++dx)
                #pragma unroll
                for (int p = 0; p < 4; ++p)
                    acc[dx][p] += a[p] * v[dx + p];
        }
        // ---- commit prefetched chunk k+1 (after this iter's barrier: safe) ----
        if (k + 1 < NK) {
            const int lb = ((k + 1) & 1) * BUF_DW;
            #pragma unroll
            for (int s = 0; s < NSLOT; ++s)
                if (s_act[s]) *(float4*)(&stg[lb + s_loff[s]]) = nf[s];
        }
    }

    // ---- epilogue: combine the two channel-half partials through LDS, scale, store ----
    __syncthreads();            // all compute reads of stg done before reuse
    if (h == 1) {
        float* dst = &stg[(w * 64 + lane) * EPS];   // stride 37 dw: conflict-free
        #pragma unroll
        for (int dx = 0; dx < 9; ++dx)
            #pragma unroll
            for (int p = 0; p < 4; ++p) dst[dx * 4 + p] = acc[dx][p];
    }
    __syncthreads();
    if (h == 0) {
        const float inv = 1.0f / (float)Cc;
        const float* src = &stg[(w * 64 + lane) * EPS];
        float* ob = out + (((size_t)bb * 81 + (3 * g + w) * 9) * Hc + (y0 + gy)) * Wc
                        + x0 + 4 * gx;
        #pragma unroll
        for (int dx = 0; dx < 9; ++dx) {
            float4 st = make_float4((acc[dx][0] + src[dx * 4 + 0]) * inv,
                                    (acc[dx][1] + src[dx * 4 + 1]) * inv,
                                    (acc[dx][2] + src[dx * 4 + 2]) * inv,
                                    (acc[dx][3] + src[dx * 4 + 3]) * inv);
            *(float4*)(ob + dx * HW) = st;
        }
    }
}

extern "C" void kernel_launch(void* const* d_in, const int* in_sizes, int n_in,
                              void* d_out, int out_size, void* d_ws, size_t ws_size,
                              hipStream_t stream) {
    const float* x1 = (const float*)d_in[0];
    const float* x2 = (const float*)d_in[1];
    float* out = (float*)d_out;
    dim3 grid(3 * 8 * 8 * Bc), block(NTHR);   // 768 blocks x 384 threads
    corr_kernel<<<grid, block, 0, stream>>>(x1, x2, out);
}

// Round 5
// 201.674 us; speedup vs baseline: 1.2585x; 1.2585x over previous
//
#include <hip/hip_runtime.h>

// FlowNet correlation: out[b, dy*9+dx, y, x] = (1/256) sum_c x1[b,c,y,x] * x2[b,c,y+dy-4,x+dx-4]
// B=4 C=256 H=W=128, 9x9 displacements, zero padding.
//
// Round-9 = round-4 structure EXACTLY (validated 102 us: 192 thr, RSC=48,
// gy=lane>>2, conflict-free-ish 2.65M, clean coalescing) + ONE change:
//   prefetch issued AFTER __syncthreads, not before.
// Rationale: __syncthreads forces s_waitcnt vmcnt(0) -> loads issued before the
// barrier are fully drained AT the barrier; the old order exposed ~500-900 cy
// of HBM/L2 latency at every one of the 64 barriers (VALUBusy stuck at 29%).
// New order: barrier -> issue k+1 loads -> compute k (covers latency) ->
// commit k+1 to the other buffer (vmcnt wait lands here, mostly satisfied).
// Same barrier-per-chunk protects WAR/RAW on the double buffer.
//
// Rounds 5-8 taught (counters, not theory): 6-wave channel-split didn't raise
// real residency (Occ 21->24%), launch_bounds(,5) spills acc (WRITE 21->525MB),
// RSC=44 is a 2-way read conflict (16.8M), row-fastest lane remap kills global
// coalescing (hbm_gbps 1.78->1.37 TB/s). All reverted.

#define MD 4
constexpr int Bc = 4, Cc = 256, Hc = 128, Wc = 128;
constexpr int TH = 16, TW = 16;
constexpr int NDY = 3;                  // dy per d-group (one per wave)
constexpr int CC = 4;                   // channels per chunk
constexpr int SROWS = TH + NDY - 1;     // 18 staged rows
constexpr int SCOLS = TW + 2 * MD;      // 24 staged cols
constexpr int RSC = 48;                 // padded row stride (dw), 48%32==16 -> clean b128
constexpr int CH_STRIDE = SROWS * RSC;  // 864 dw per channel
constexpr int BUF_DW = CC * CH_STRIDE;  // 3456 dw per buffer
constexpr int NF4 = CC * SROWS * (SCOLS / 4);  // 432 float4 staging slots
constexpr int NTHR = 192;
constexpr int NSLOT = 3;                // ceil(432/192)
constexpr int NK = Cc / CC;             // 64 chunks

__global__ __launch_bounds__(NTHR, 4)
void corr_kernel(const float* __restrict__ x1, const float* __restrict__ x2,
                 float* __restrict__ out)
{
    __shared__ float stg[2 * BUF_DW];   // 27648 B

    const int tid  = threadIdx.x;
    const int w    = tid >> 6;          // wave id = local dy
    const int lane = tid & 63;
    const int gy   = lane >> 2;         // 0..15 tile row
    const int gx   = lane & 3;          // 0..3  col-group (4 px each)

    // ---- XCD-aware swizzle: g-siblings (same tile) differ by +8 in bid -> same XCD ----
    const int bid  = blockIdx.x;
    const int q    = bid / 24;
    const int r    = bid - q * 24;
    const int g    = r >> 3;            // d-group 0..2
    const int t    = q * 8 + (r & 7);   // tile index 0..255
    const int tx = t & 7;
    const int ty = (t >> 3) & 7;
    const int bb = t >> 6;
    const int x0 = tx * TW, y0 = ty * TH;
    const int rowbase = y0 + 3 * g - MD;   // global y of staged row 0

    // ---- hoisted staging slot descriptors (fixed per thread across chunks) ----
    int  s_goff[NSLOT], s_loff[NSLOT];
    bool s_val[NSLOT], s_act[NSLOT];
    #pragma unroll
    for (int s = 0; s < NSLOT; ++s) {
        int idx = tid + s * NTHR;
        bool active = idx < NF4;
        int i2  = active ? idx : 0;
        int cl  = i2 / (SROWS * 6);
        int rem = i2 - cl * (SROWS * 6);
        int rr  = rem / 6;
        int gc  = rem - rr * 6;
        int yy  = rowbase + rr;
        int xx  = x0 - 4 + 4 * gc;          // multiple of 4: float4 all-valid or all-invalid
        s_act[s]  = active;
        s_val[s]  = active && ((unsigned)yy < (unsigned)Hc) && ((unsigned)xx < (unsigned)(Wc - 3));
        s_goff[s] = cl * (Hc * Wc) + yy * Wc + xx;
        s_loff[s] = cl * CH_STRIDE + rr * RSC + 4 * gc;
    }

    const float* x2b = x2 + (size_t)bb * Cc * Hc * Wc;
    const float* x1b = x1 + (((size_t)bb * Cc) * Hc + (y0 + gy)) * Wc + x0 + 4 * gx;

    float acc[9][4];
    #pragma unroll
    for (int dx = 0; dx < 9; ++dx)
        #pragma unroll
        for (int p = 0; p < 4; ++p) acc[dx][p] = 0.f;

    const float4 f40 = make_float4(0.f, 0.f, 0.f, 0.f);
    float4 nf[NSLOT];

    // ---- prologue: stage chunk 0 into buffer 0 ----
    #pragma unroll
    for (int s = 0; s < NSLOT; ++s) {
        nf[s] = f40;
        if (s_val[s]) nf[s] = *(const float4*)(x2b + s_goff[s]);
    }
    #pragma unroll
    for (int s = 0; s < NSLOT; ++s)
        if (s_act[s]) *(float4*)(&stg[s_loff[s]]) = nf[s];

    for (int k = 0; k < NK; ++k) {
        const int pb = k & 1;
        __syncthreads();   // chunk k's buffer fully written; prev buffer's readers done
        // ---- issue global x2 prefetch for chunk k+1 AFTER the barrier: its
        //      latency is covered by the compute below instead of being drained
        //      by the barrier's implicit s_waitcnt vmcnt(0). ----
        if (k + 1 < NK) {
            const int gof = (k + 1) * CC * Hc * Wc;
            #pragma unroll
            for (int s = 0; s < NSLOT; ++s) {
                nf[s] = f40;
                if (s_val[s]) nf[s] = *(const float4*)(x2b + gof + s_goff[s]);
            }
        }
        // ---- compute chunk k (x1 loaded inline: L1/L2 hits, no reg pressure) ----
        #pragma unroll
        for (int cl = 0; cl < CC; ++cl) {
            const int c = k * CC + cl;
            const float4 a4 = *(const float4*)(x1b + c * (Hc * Wc));
            const float* rowp = &stg[pb * BUF_DW + cl * CH_STRIDE + (gy + w) * RSC + 4 * gx];
            const float4 q0 = *(const float4*)(rowp);
            const float4 q1 = *(const float4*)(rowp + 4);
            const float4 q2 = *(const float4*)(rowp + 8);
            const float v[12] = {q0.x, q0.y, q0.z, q0.w,
                                 q1.x, q1.y, q1.z, q1.w,
                                 q2.x, q2.y, q2.z, q2.w};
            const float a[4] = {a4.x, a4.y, a4.z, a4.w};
            #pragma unroll
            for (int dx = 0; dx < 9; ++dx)
                #pragma unroll
                for (int p = 0; p < 4; ++p)
                    acc[dx][p] += a[p] * v[dx + p];
        }
        // ---- commit prefetched chunk k+1 (vmcnt wait lands here, after compute) ----
        if (k + 1 < NK) {
            const int lb = ((k + 1) & 1) * BUF_DW;
            #pragma unroll
            for (int s = 0; s < NSLOT; ++s)
                if (s_act[s]) *(float4*)(&stg[lb + s_loff[s]]) = nf[s];
        }
    }

    // ---- epilogue: scale and store 9 aligned float4 per thread ----
    const float inv = 1.0f / (float)Cc;
    float* ob = out + (((size_t)bb * 81 + (3 * g + w) * 9) * Hc + (y0 + gy)) * Wc + x0 + 4 * gx;
    #pragma unroll
    for (int dx = 0; dx < 9; ++dx) {
        float4 st = make_float4(acc[dx][0] * inv, acc[dx][1] * inv,
                                acc[dx][2] * inv, acc[dx][3] * inv);
        *(float4*)(ob + dx * (Hc * Wc)) = st;
    }
}

extern "C" void kernel_launch(void* const* d_in, const int* in_sizes, int n_in,
                              void* d_out, int out_size, void* d_ws, size_t ws_size,
                              hipStream_t stream) {
    const float* x1 = (const float*)d_in[0];
    const float* x2 = (const float*)d_in[1];
    float* out = (float*)d_out;
    dim3 grid(3 * 8 * 8 * Bc), block(NTHR);   // 768 blocks x 192 threads
    corr_kernel<<<grid, block, 0, stream>>>(x1, x2, out);
}